// Round 9
// baseline (1195.296 us; speedup 1.0000x reference)
//
#include <hip/hip_runtime.h>
#include <hip/hip_bf16.h>
#include <math.h>

// dtype resolved empirically: all float inputs fp32, output fp32.
// GEMMs run as bf16 MFMA (threshold 2.5e-2 sized for bf16 compute; absmax 0.0078 @ R5/R6).
// R6 lesson: dt must be computed inside the scan (dtPre global round-trip = 3.4x FETCH).
// R7: B/C staged to LDS fp16 in phase 0 -> phases 1/3 pure LDS+math. 62->53us.
// R8 FAILED: 512-thread/2-d scan blocks (barrier radius doubled). 53->57us.
// R9 FAILED: RMS fused into BOTH small+wide GEMMs; 48-colblock mlp_w1 recompute dominated.
// R10 WIN: SwiGLU row-interleave pack (MODE 4/5), u12 fp32->bf16. 1494->1307us.
// R11 WIN: all-layer cvt hoist + scan 2-d/block (shared B/C staging). 1307->1177us.
// R12: k_cond split WIN; scan 4-d/block FAILED (occupancy 52->19%). 2-d is the sweet spot.
// R13 WIN: scan reverted to R11 2-d verbatim. 1283->1159us.
// R14 FAILED net (+24us): ysT [b,k,l,d] made scan stores stride-384 8B partial-line writes
//     -> WRITE_SIZE 6->24.5MB, scan +3.5us x8. LESSON: write-side coalescing first; scattered
//     READS share L2 lines across blocks, scattered WRITES pay full-line write-back.
//     rms1->gemm_in fusion (6 col-blocks only) was the non-regressing half; kept.
// R15: revert scan store + merge_ln to R13 [b,k,d,l]; keep rms1 ASRC=2 fusion.

#define DEV __device__ __forceinline__

typedef __bf16 bf16_t;
typedef __attribute__((ext_vector_type(8))) __bf16 bf16x8;
typedef __attribute__((ext_vector_type(4))) float f32x4;
typedef __attribute__((ext_vector_type(2))) _Float16 h2;

DEV float siluf(float x){ return x / (1.f + __expf(-x)); }
DEV float softplusf(float x){ return fmaxf(x, 0.f) + __logf(1.f + __expf(-fabsf(x))); }

// scan-order permutation: scan position l of direction k reads spatial row perm_idx(k,l)
DEV int perm_idx(int k, int l){
  switch(k & 3){
    case 0: return l;
    case 1: return 255 - l;
    case 2: return ((l & 15) << 4) | (l >> 4);
    default: { int r = 255 - l; return ((r & 15) << 4) | (r >> 4); }
  }
}

// ---------- weight fp32 -> bf16 cast ----------
// segments (elements): in_w 147456 | outp_w 147456 | mlp_w1 1179648 | mlp_w2 589824 | xproj 86016
// mlp_w1 rows interleaved for SwiGLU pack: dst row c: q=c>>5, t=c&31,
// src row = t<16 ? q*16+t : 1536 + q*16 + (t-16).
DEV void cvt_one(int idx, const float* inw, const float* outw, const float* w1,
                 const float* w2, const float* xp, bf16_t* dst){
  const float* src; int off;
  if (idx < 147456){ src = inw;  off = idx; }
  else if (idx < 294912){ src = outw; off = idx - 147456; }
  else if (idx < 1474560){
    int o = idx - 294912;
    int rowc = o / 384, col = o - rowc*384;
    int q = rowc >> 5, tt = rowc & 31;
    int srow = (tt < 16) ? (q*16 + tt) : (1536 + q*16 + (tt - 16));
    src = w1; off = srow*384 + col;
  }
  else if (idx < 2064384){ src = w2; off = idx - 1474560; }
  else { src = xp; off = idx - 2064384; }
  float4 v = *(const float4*)(src + off);
  union { bf16_t h[4]; uint2 u; } cv;
  cv.h[0] = (bf16_t)v.x; cv.h[1] = (bf16_t)v.y; cv.h[2] = (bf16_t)v.z; cv.h[3] = (bf16_t)v.w;
  *(uint2*)(dst + idx) = cv.u;
}

__global__ void k_cvt_layer(const float* __restrict__ inw, const float* __restrict__ outw,
                            const float* __restrict__ w1, const float* __restrict__ w2,
                            const float* __restrict__ xp, bf16_t* __restrict__ dst){
  int idx = (blockIdx.x*256 + threadIdx.x)*4;   // 2150400 per layer
  cvt_one(idx, inw, outw, w1, w2, xp, dst);
}

// all 8 layers in one dispatch: 2100 blocks per layer
__global__ void k_cvt_all(const float* __restrict__ inw, const float* __restrict__ outw,
                          const float* __restrict__ w1, const float* __restrict__ w2,
                          const float* __restrict__ xp, bf16_t* __restrict__ dst){
  int layer = blockIdx.x / 2100;
  int within = blockIdx.x % 2100;
  int idx = (within*256 + threadIdx.x)*4;
  cvt_one(idx, inw + (size_t)layer*147456, outw + (size_t)layer*147456,
          w1 + (size_t)layer*1179648, w2 + (size_t)layer*589824,
          xp + (size_t)layer*86016, dst + (size_t)layer*2150400);
}

// ---------- conditioning (R12: split + vectorized) ----------
__global__ void k_cond1(const float* __restrict__ t, const float* __restrict__ tw1,
                        const float* __restrict__ tb1, float* __restrict__ h1g){
  int b = blockIdx.x / 3, ch = blockIdx.x % 3;   // grid 12, block 128
  int tid = threadIdx.x;
  int o = ch*128 + tid;
  __shared__ float temb[256];
  float tv = t[b];
  {
    float f = __expf(-logf(10000.f) * (float)tid / 128.f);
    float a = tv * f;
    temb[tid] = cosf(a); temb[128 + tid] = sinf(a);
  }
  __syncthreads();
  const float4* te = (const float4*)temb;
  const float4* wp = (const float4*)(tw1 + (size_t)o*256);
  float acc = tb1[o];
  #pragma unroll 8
  for (int j = 0; j < 64; j++){
    float4 c4 = te[j], w4 = wp[j];
    acc += c4.x*w4.x + c4.y*w4.y + c4.z*w4.z + c4.w*w4.w;
  }
  h1g[b*384 + o] = siluf(acc);
}

__global__ void k_cond2(const int* __restrict__ y, const float* __restrict__ h1g,
                        const float* __restrict__ tw2, const float* __restrict__ tb2,
                        const float* __restrict__ ytab, float* __restrict__ sc){
  int b = blockIdx.x / 3, ch = blockIdx.x % 3;   // grid 12, block 128
  int tid = threadIdx.x;
  int o = ch*128 + tid;
  __shared__ float h1[384];
  h1[tid] = h1g[b*384 + tid];
  h1[tid + 128] = h1g[b*384 + tid + 128];
  h1[tid + 256] = h1g[b*384 + tid + 256];
  __syncthreads();
  const float4* hp = (const float4*)h1;
  const float4* wp = (const float4*)(tw2 + (size_t)o*384);
  float acc = tb2[o];
  #pragma unroll 8
  for (int j = 0; j < 96; j++){
    float4 c4 = hp[j], w4 = wp[j];
    acc += c4.x*w4.x + c4.y*w4.y + c4.z*w4.z + c4.w*w4.w;
  }
  float c = acc + ytab[(size_t)y[b]*384 + o];
  sc[b*384 + o] = siluf(c);
}

// ---------- patch embed + pos embed ----------
__global__ void k_patch(const float* __restrict__ x, const float* __restrict__ pw1,
                        const float* __restrict__ pw2, const float* __restrict__ pb2,
                        const float* __restrict__ pos, float* __restrict__ h){
  int bl = blockIdx.x; int b = bl >> 8; int l = bl & 255;
  int gh = l >> 4, gw = l & 15;
  __shared__ float xp[12]; __shared__ float tmp[128];
  int tid = threadIdx.x;  // block 384
  if (tid < 12){
    int ci = tid >> 2, ph = (tid >> 1) & 1, pw = tid & 1;
    xp[tid] = x[((size_t)(b*3 + ci)*32 + gh*2 + ph)*32 + gw*2 + pw];
  }
  __syncthreads();
  if (tid < 128){
    float a = 0.f;
    #pragma unroll
    for (int k = 0; k < 12; k++) a += xp[k] * pw1[tid*12 + k];
    tmp[tid] = a;
  }
  __syncthreads();
  float a = pb2[tid];
  for (int j = 0; j < 128; j++) a += tmp[j] * pw2[(size_t)tid*128 + j];
  h[(size_t)(b*256 + l)*384 + tid] = a + pos[(size_t)l*384 + tid];
}

// ---------- small linear ----------
__global__ void k_lin_small(const float* __restrict__ sc, const float* __restrict__ W,
                            const float* __restrict__ bias, float* __restrict__ out, int N){
  int idx = blockIdx.x * blockDim.x + threadIdx.x;
  if (idx >= 4*N) return;
  int b = idx / N, o = idx % N;
  const float4* cp = (const float4*)(sc + b*384);
  const float4* wp = (const float4*)(W + (size_t)o*384);
  float a = bias[o];
  #pragma unroll 4
  for (int k = 0; k < 96; k++){
    float4 c4 = cp[k], w4 = wp[k];
    a += c4.x*w4.x + c4.y*w4.y + c4.z*w4.z + c4.w*w4.w;
  }
  out[idx] = a;
}

// ---------- RMSNorm + adaLN modulate -> bf16 ----------
__global__ void k_rms_mod(const float* __restrict__ h, const float* __restrict__ nw,
                          const float* __restrict__ modBase, bf16_t* __restrict__ out){
  int bl = blockIdx.x; int b = bl >> 8;
  const float* hp = h + (size_t)bl*384;
  const float* mp = modBase + (size_t)b*18432;
  __shared__ float red[2];
  int tid = threadIdx.x;  // block 128
  float v[3]; float ss = 0.f;
  #pragma unroll
  for (int ii = 0; ii < 3; ii++){ v[ii] = hp[tid + ii*128]; ss += v[ii]*v[ii]; }
  #pragma unroll
  for (int off = 32; off; off >>= 1) ss += __shfl_down(ss, off);
  if ((tid & 63) == 0) red[tid >> 6] = ss;
  __syncthreads();
  ss = red[0] + red[1];
  float inv = rsqrtf(ss / 384.f + 1e-6f);
  #pragma unroll
  for (int ii = 0; ii < 3; ii++){
    int d = tid + ii*128;
    float xv = v[ii] * inv * nw[d];
    out[(size_t)bl*384 + d] = (bf16_t)(xv * (1.f + mp[384 + d]) + mp[d]);
  }
}

// ---------- bf16 MFMA GEMM: C[M,N] = A[M,K] @ W[N,K]^T ----------
// MODE 0: C = acc (fp32)
// MODE 2: C += gate*acc (gate = modBase[(row>>8)*18432 + col])
// MODE 4: SwiGLU pack (W rows pre-interleaved): Cb[row][p] = bf16(silu(u1+b[p])*(u2+b[N/2+p]))
// MODE 5: C += gate*(acc + bias)
// ASRC 0: A is bf16; ASRC 2: A fp32 + RMSNorm(nw) + modulate (shift=modRms[b*18432+d],
//   scale=modRms[b*18432+384+d]). ONLY for narrow-N GEMMs (R9 lesson: recompute x colblocks).
template<int MODE, int ASRC>
__global__ __launch_bounds__(256) void k_gemm_bf(
    const void* __restrict__ Avoid, const bf16_t* __restrict__ W,
    const float* __restrict__ bias, float* __restrict__ C,
    const float* __restrict__ modBase, const float* __restrict__ nw,
    const float* __restrict__ modRms, int N, int K, int Nstore){
  __shared__ bf16_t As[2][64*40];
  __shared__ bf16_t Ws[2][64*40];
  const int tid = threadIdx.x;
  const int bm = blockIdx.y * 64, bn = blockIdx.x * 64;
  const int wave = tid >> 6, lane = tid & 63;
  const int m16 = lane & 15, kg = lane >> 4;
  const int r = tid >> 2, seg = tid & 3;
  const int nt = K / 32;

  float inv = 0.f;
  if constexpr (ASRC == 2){
    // pre-pass: sum of squares over row bm+r (4 seg-threads each cover 96 elems)
    const float* hp = (const float*)Avoid + (size_t)(bm + r)*K + seg*8;
    float ss = 0.f;
    for (int kt = 0; kt < nt; kt++){
      float4 a4 = *(const float4*)(hp + kt*32);
      float4 b4 = *(const float4*)(hp + kt*32 + 4);
      ss += a4.x*a4.x + a4.y*a4.y + a4.z*a4.z + a4.w*a4.w
          + b4.x*b4.x + b4.y*b4.y + b4.z*b4.z + b4.w*b4.w;
    }
    ss += __shfl_xor(ss, 1);
    ss += __shfl_xor(ss, 2);
    inv = rsqrtf(ss / 384.f + 1e-6f);
  }

  uint4 aP, wP;
  auto loadT = [&](int kt){
    wP = *(const uint4*)(W + (size_t)(bn + r)*K + kt*32 + seg*8);
    if constexpr (ASRC == 2){
      const float* Ap = (const float*)Avoid + (size_t)(bm + r)*K + kt*32 + seg*8;
      float4 a4 = *(const float4*)(Ap), b4 = *(const float4*)(Ap + 4);
      int d0 = kt*32 + seg*8;
      const float* mp = modRms + (size_t)(bm >> 8)*18432;
      float4 n0 = *(const float4*)(nw + d0),        n1 = *(const float4*)(nw + d0 + 4);
      float4 sh0 = *(const float4*)(mp + d0),       sh1 = *(const float4*)(mp + d0 + 4);
      float4 sc0 = *(const float4*)(mp + 384 + d0), sc1 = *(const float4*)(mp + 384 + d0 + 4);
      union { bf16_t h[8]; uint4 u; } pk;
      pk.h[0] = (bf16_t)((a4.x*inv*n0.x)*(1.f + sc0.x) + sh0.x);
      pk.h[1] = (bf16_t)((a4.y*inv*n0.y)*(1.f + sc0.y) + sh0.y);
      pk.h[2] = (bf16_t)((a4.z*inv*n0.z)*(1.f + sc0.z) + sh0.z);
      pk.h[3] = (bf16_t)((a4.w*inv*n0.w)*(1.f + sc0.w) + sh0.w);
      pk.h[4] = (bf16_t)((b4.x*inv*n1.x)*(1.f + sc1.x) + sh1.x);
      pk.h[5] = (bf16_t)((b4.y*inv*n1.y)*(1.f + sc1.y) + sh1.y);
      pk.h[6] = (bf16_t)((b4.z*inv*n1.z)*(1.f + sc1.z) + sh1.z);
      pk.h[7] = (bf16_t)((b4.w*inv*n1.w)*(1.f + sc1.w) + sh1.w);
      aP = pk.u;
    } else {
      aP = *(const uint4*)((const bf16_t*)Avoid + (size_t)(bm + r)*K + kt*32 + seg*8);
    }
  };
  auto stash = [&](int buf){
    *(uint4*)&As[buf][r*40 + seg*8] = aP;
    *(uint4*)&Ws[buf][r*40 + seg*8] = wP;
  };

  f32x4 acc[4] = {};
  loadT(0); stash(0); __syncthreads();
  for (int kt = 0; kt < nt; kt++){
    int buf = kt & 1;
    if (kt + 1 < nt) loadT(kt + 1);
    bf16x8 af = *(bf16x8*)&As[buf][(wave*16 + m16)*40 + kg*8];
    #pragma unroll
    for (int j = 0; j < 4; j++){
      bf16x8 bfr = *(bf16x8*)&Ws[buf][(j*16 + m16)*40 + kg*8];
      acc[j] = __builtin_amdgcn_mfma_f32_16x16x32_bf16(af, bfr, acc[j], 0, 0, 0);
    }
    if (kt + 1 < nt) stash(buf ^ 1);
    __syncthreads();
  }

  // C/D layout: col = lane&15, row = (lane>>4)*4 + reg
  if constexpr (MODE == 4){
    bf16_t* Cb = (bf16_t*)C;
    const int Np = N >> 1;    // 1536
    #pragma unroll
    for (int jp = 0; jp < 2; jp++){
      int pcol = (bn >> 1) + jp*16 + m16;
      float b1v = bias[pcol], b2v = bias[Np + pcol];
      #pragma unroll
      for (int rg = 0; rg < 4; rg++){
        int row = bm + wave*16 + kg*4 + rg;
        float u1v = acc[jp*2][rg] + b1v;
        float u2v = acc[jp*2 + 1][rg] + b2v;
        Cb[(size_t)row*Np + pcol] = (bf16_t)(siluf(u1v)*u2v);
      }
    }
  } else {
    #pragma unroll
    for (int j = 0; j < 4; j++){
      int col = bn + j*16 + m16;
      if (col < Nstore){
        #pragma unroll
        for (int rg = 0; rg < 4; rg++){
          int row = bm + wave*16 + kg*4 + rg;
          float v = acc[j][rg];
          if constexpr (MODE == 5) v += bias[col];
          if constexpr (MODE == 2 || MODE == 5)
            C[(size_t)row*N + col] += modBase[(size_t)(row >> 8)*18432 + col] * v;
          else
            C[(size_t)row*N + col] = v;
        }
      }
    }
  }
}

// ---------- depthwise 3x3 conv + bias + silu; writes fp32 + bf16 copies ----------
__global__ void k_conv(const float* __restrict__ z, const float* __restrict__ cw,
                       const float* __restrict__ cb, float* __restrict__ convT,
                       bf16_t* __restrict__ convB){
  int bl = blockIdx.x; int b = bl >> 8, l = bl & 255;
  int hh = l >> 4, ww = l & 15;
  int d = threadIdx.x;  // 384
  float acc = cb[d];
  #pragma unroll
  for (int kh = 0; kh < 3; kh++){
    int yy = hh + kh - 1; if ((unsigned)yy > 15u) continue;
    #pragma unroll
    for (int kw = 0; kw < 3; kw++){
      int xx = ww + kw - 1; if ((unsigned)xx > 15u) continue;
      acc += z[(size_t)(b*256 + yy*16 + xx)*384 + d] * cw[d*9 + kh*3 + kw];
    }
  }
  float s = siluf(acc);
  convT[(size_t)bl*384 + d] = s;
  convB[(size_t)bl*384 + d] = (bf16_t)s;
}

// ---------- fused dt + chunked selective scan -> ysT[b,k,d,l_scan] ----------
// xdblS layout: [b][lsp][224] cols k*56 + {dtr 0..23 | B 24..39 | C 40..55}
// R11 structure (measured best): 2 d-channels per 256-thread block (3072 blocks).
// B/C fp16 staging (18.4KB) shared by both d's; convT read as float2; phase 1/3 run
// two independent chains per thread; phase 2 uses 32 lanes. Barrier radius 256 (R8 lesson).
// Occupancy curve measured: 1-d/block 45% / 2-d 52% / 4-d 19%. 2-d wins.
// Output [b,k,d,l] COALESCED stores (R14 lesson: partial-line writes 4x WRITE_SIZE).
__global__ __launch_bounds__(256) void k_scan(
    const float* __restrict__ xdblS, const float* __restrict__ convT,
    const float* __restrict__ dtw, const float* __restrict__ dtb,
    const float* __restrict__ Alog, const float* __restrict__ Dsw,
    float* __restrict__ ysT){
  int blk = blockIdx.x;                 // b*768 + k*192 + dp
  int dp = blk % 192; int k = (blk / 192) & 3; int b = blk / 768;
  int d0 = dp*2;
  int tid = threadIdx.x;
  int n = tid & 15, chunk = tid >> 4;
  __shared__ float sdt[2][256], sxv[2][256], sy[2][256];
  __shared__ float sA[2][16][17], sBc[2][16][17], sPre[2][16][17];
  __shared__ _Float16 sB16[256*18];
  __shared__ _Float16 sC16[256*18];

  // phase 0: dt = softplus(dtr . dtw_row + dtb) for both d's; stage x2, B, C
  {
    int l = tid;
    int lp = perm_idx(k, l);
    const float* row = xdblS + (size_t)(b*256 + lp)*224 + k*56;
    const float4* xr = (const float4*)(row);
    float4 x0 = xr[0], x1 = xr[1], x2 = xr[2], x3 = xr[3], x4 = xr[4], x5 = xr[5];
    #pragma unroll
    for (int j = 0; j < 2; j++){
      const float4* w = (const float4*)(dtw + ((size_t)k*384 + d0 + j)*24);
      float4 w0 = w[0], w1 = w[1], w2 = w[2], w3 = w[3], w4 = w[4], w5 = w[5];
      float a0 = dtb[k*384 + d0 + j];
      a0 += x0.x*w0.x + x0.y*w0.y + x0.z*w0.z + x0.w*w0.w;
      a0 += x1.x*w1.x + x1.y*w1.y + x1.z*w1.z + x1.w*w1.w;
      a0 += x2.x*w2.x + x2.y*w2.y + x2.z*w2.z + x2.w*w2.w;
      a0 += x3.x*w3.x + x3.y*w3.y + x3.z*w3.z + x3.w*w3.w;
      a0 += x4.x*w4.x + x4.y*w4.y + x4.z*w4.z + x4.w*w4.w;
      a0 += x5.x*w5.x + x5.y*w5.y + x5.z*w5.z + x5.w*w5.w;
      sdt[j][l] = softplusf(a0);
    }
    float2 xv2 = *(const float2*)(convT + (size_t)(b*256 + lp)*384 + d0);
    sxv[0][l] = xv2.x; sxv[1][l] = xv2.y;
    const float4* bp = (const float4*)(row + 24);   // bp[0..3]=B, bp[4..7]=C
    h2* bl = (h2*)(sB16 + l*18);
    h2* cl = (h2*)(sC16 + l*18);
    #pragma unroll
    for (int q = 0; q < 4; q++){
      float4 bv = bp[q];
      h2 p0; p0[0] = (_Float16)bv.x; p0[1] = (_Float16)bv.y;
      h2 p1; p1[0] = (_Float16)bv.z; p1[1] = (_Float16)bv.w;
      bl[q*2] = p0; bl[q*2+1] = p1;
      float4 cv = bp[q+4];
      h2 q0; q0[0] = (_Float16)cv.x; q0[1] = (_Float16)cv.y;
      h2 q1; q1[0] = (_Float16)cv.z; q1[1] = (_Float16)cv.w;
      cl[q*2] = q0; cl[q*2+1] = q1;
    }
  }
  __syncthreads();

  float av[2], Dv[2];
  #pragma unroll
  for (int j = 0; j < 2; j++){
    av[j] = -__expf(Alog[((size_t)(k*384) + d0 + j)*16 + n]);
    Dv[j] = Dsw[k*384 + d0 + j];
  }

  // phase 1: local chunk scan from zero state, two chains
  float dA[2][16], dBu[2][16];
  float Ap[2] = {1.f, 1.f}, hl[2] = {0.f, 0.f};
  #pragma unroll
  for (int i = 0; i < 16; i++){
    int l = chunk*16 + i;
    float bn16 = (float)sB16[l*18 + n];
    #pragma unroll
    for (int j = 0; j < 2; j++){
      float dtv = sdt[j][l];
      float e = __expf(dtv * av[j]);
      float u = dtv * sxv[j][l] * bn16;
      dA[j][i] = e; dBu[j][i] = u;
      Ap[j] *= e; hl[j] = e*hl[j] + u;
    }
  }
  #pragma unroll
  for (int j = 0; j < 2; j++){ sA[j][chunk][n] = Ap[j]; sBc[j][chunk][n] = hl[j]; }
  __syncthreads();

  // phase 2: carry scan across 16 chunks (32 lanes: 16 per d)
  if (tid < 32){
    int j = tid >> 4, nn = tid & 15;
    float carry = 0.f;
    #pragma unroll
    for (int c = 0; c < 16; c++){
      sPre[j][c][nn] = carry;
      carry = sA[j][c][nn]*carry + sBc[j][c][nn];
    }
  }
  __syncthreads();

  // phase 3: replay; reduce over n; stage into sy
  float hh[2] = {sPre[0][chunk][n], sPre[1][chunk][n]};
  #pragma unroll
  for (int i = 0; i < 16; i++){
    int l = chunk*16 + i;
    float cn = (float)sC16[l*18 + n];
    hh[0] = dA[0][i]*hh[0] + dBu[0][i];
    hh[1] = dA[1][i]*hh[1] + dBu[1][i];
    float p0 = hh[0]*cn, p1 = hh[1]*cn;
    p0 += __shfl_xor(p0, 1); p1 += __shfl_xor(p1, 1);
    p0 += __shfl_xor(p0, 2); p1 += __shfl_xor(p1, 2);
    p0 += __shfl_xor(p0, 4); p1 += __shfl_xor(p1, 4);
    p0 += __shfl_xor(p0, 8); p1 += __shfl_xor(p1, 8);
    if (n == 0){
      sy[0][l] = p0 + Dv[0]*sxv[0][l];
      sy[1][l] = p1 + Dv[1]*sxv[1][l];
    }
  }
  __syncthreads();
  // coalesced writes: ysT[b,k,d,l]
  ysT[((size_t)(b*4 + k)*384 + d0)*256 + tid] = sy[0][tid];
  ysT[((size_t)(b*4 + k)*384 + d0 + 1)*256 + tid] = sy[1][tid];
}

// ---------- merge 4 directions + LayerNorm(onorm) -> bf16 (ysT[b,k,d,l_scan]) ----------
__global__ void k_merge_ln(const float* __restrict__ ysT, const float* __restrict__ ow,
                           const float* __restrict__ ob, bf16_t* __restrict__ out){
  int bl = blockIdx.x; int b = bl >> 8; int l = bl & 255;
  int tl = ((l & 15) << 4) | (l >> 4);
  int i2 = 255 - l, i4 = 255 - tl;
  __shared__ float red[4];
  int tid = threadIdx.x;  // block 128
  const float* base = ysT + (size_t)b*4*384*256;
  float v[3]; float s = 0.f, s2 = 0.f;
  #pragma unroll
  for (int ii = 0; ii < 3; ii++){
    int d = tid + ii*128;
    float vv = base[(size_t)d*256 + l]
             + base[(size_t)(384 + d)*256 + i2]
             + base[(size_t)(768 + d)*256 + tl]
             + base[(size_t)(1152 + d)*256 + i4];
    v[ii] = vv; s += vv; s2 += vv*vv;
  }
  #pragma unroll
  for (int off = 32; off; off >>= 1){ s += __shfl_down(s, off); s2 += __shfl_down(s2, off); }
  if ((tid & 63) == 0){ red[tid >> 6] = s; red[2 + (tid >> 6)] = s2; }
  __syncthreads();
  s = red[0] + red[1]; s2 = red[2] + red[3];
  float mu = s / 384.f;
  float var = s2 / 384.f - mu*mu;
  float inv = rsqrtf(var + 1e-5f);
  #pragma unroll
  for (int ii = 0; ii < 3; ii++){
    int d = tid + ii*128;
    out[(size_t)bl*384 + d] = (bf16_t)((v[ii] - mu) * inv * ow[d] + ob[d]);
  }
}

// ---------- final: ln_na + modulate + f_lin + unpatchify ----------
__global__ void k_final(const float* __restrict__ h, const float* __restrict__ modf,
                        const float* __restrict__ flw, const float* __restrict__ flb,
                        float* __restrict__ out){
  int bl = blockIdx.x; int b = bl >> 8; int l = bl & 255;
  int tid = threadIdx.x;  // block 128
  __shared__ float buf[384]; __shared__ float red[4];
  const float* hp = h + (size_t)bl*384;
  float v[3]; float s = 0.f, s2 = 0.f;
  #pragma unroll
  for (int ii = 0; ii < 3; ii++){ float xv = hp[tid + ii*128]; v[ii] = xv; s += xv; s2 += xv*xv; }
  #pragma unroll
  for (int off = 32; off; off >>= 1){ s += __shfl_down(s, off); s2 += __shfl_down(s2, off); }
  if ((tid & 63) == 0){ red[tid >> 6] = s; red[2 + (tid >> 6)] = s2; }
  __syncthreads();
  s = red[0] + red[1]; s2 = red[2] + red[3];
  float mu = s / 384.f;
  float var = s2 / 384.f - mu*mu;
  float inv = rsqrtf(var + 1e-6f);
  #pragma unroll
  for (int ii = 0; ii < 3; ii++){
    int d = tid + ii*128;
    buf[d] = (v[ii] - mu) * inv * (1.f + modf[b*768 + 384 + d]) + modf[b*768 + d];
  }
  __syncthreads();
  if (tid < 12){
    float a = flb[tid];
    for (int k = 0; k < 384; k++) a += buf[k] * flw[(size_t)tid*384 + k];
    int p = tid / 6, q = (tid / 3) & 1, cc = tid % 3;
    int gh = l >> 4, gw = l & 15;
    out[((size_t)(b*3 + cc)*32 + gh*2 + p)*32 + gw*2 + q] = a;
  }
}

extern "C" void kernel_launch(void* const* d_in, const int* in_sizes, int n_in,
                              void* d_out, int out_size, void* d_ws, size_t ws_size,
                              hipStream_t stream){
  const float* x       = (const float*)d_in[0];
  const float* t       = (const float*)d_in[1];
  const int*   y       = (const int*)  d_in[2];
  const float* t_w1    = (const float*)d_in[3];
  const float* t_b1    = (const float*)d_in[4];
  const float* t_w2    = (const float*)d_in[5];
  const float* t_b2    = (const float*)d_in[6];
  const float* y_table = (const float*)d_in[7];
  const float* pe_w1   = (const float*)d_in[8];
  const float* pe_w2   = (const float*)d_in[9];
  const float* pe_b2   = (const float*)d_in[10];
  const float* pos     = (const float*)d_in[11];
  const float* adaln_w = (const float*)d_in[12];
  const float* adaln_b = (const float*)d_in[13];
  const float* n1_w    = (const float*)d_in[14];
  const float* n2_w    = (const float*)d_in[15];
  const float* in_w    = (const float*)d_in[16];
  const float* conv_w  = (const float*)d_in[17];
  const float* conv_b  = (const float*)d_in[18];
  const float* xproj_w = (const float*)d_in[19];
  const float* dt_w    = (const float*)d_in[20];
  const float* dt_b    = (const float*)d_in[21];
  const float* A_logs  = (const float*)d_in[22];
  const float* Ds      = (const float*)d_in[23];
  const float* onorm_w = (const float*)d_in[24];
  const float* onorm_b = (const float*)d_in[25];
  const float* outp_w  = (const float*)d_in[26];
  const float* mlp_w1  = (const float*)d_in[27];
  const float* mlp_b1  = (const float*)d_in[28];
  const float* mlp_w2  = (const float*)d_in[29];
  const float* mlp_b2  = (const float*)d_in[30];
  const float* f_adaln_w = (const float*)d_in[31];
  const float* f_adaln_b = (const float*)d_in[32];
  const float* f_lin_w = (const float*)d_in[33];
  const float* f_lin_b = (const float*)d_in[34];

  float* ws = (float*)d_ws;
  float*  sc      = ws + 0;         // 1536
  float*  h       = ws + 1536;      // 393216
  float*  modAll  = ws + 394752;    // 73728 (4 x 18432)
  float*  modf    = ws + 468480;    // 3072
  float*  buf1    = ws + 471552;    // 393216 (z)
  float*  convT   = ws + 864768;    // 393216
  float*  xdblS   = ws + 1257984;   // 229376 (4 x 256 x 224)
  bf16_t* u12b    = (bf16_t*)(ws + 1487360);   // 1572864 bf16 (786432 fl)
  float*  ysT     = ws + 2273792;   // 1572864 (layout [b][k][d][l])
  bf16_t* xin_bf  = (bf16_t*)(ws + 3846656);   // 393216 bf16
  bf16_t* ssin_bf = (bf16_t*)(ws + 4043264);   // 393216 bf16
  bf16_t* conv_bf = (bf16_t*)(ws + 4239872);   // 393216 bf16
  bf16_t* wbfBase = (bf16_t*)(ws + 4436480);   // big: 8x2150400 bf16; small: 1x
  float*  h1g     = ysT;            // 1536 fl scratch (ysT unused until first scan)

  const bool bigws = ws_size >= (size_t)13038080 * 4;

  k_cond1<<<dim3(12), dim3(128), 0, stream>>>(t, t_w1, t_b1, h1g);
  k_cond2<<<dim3(12), dim3(128), 0, stream>>>(y, h1g, t_w2, t_b2, y_table, sc);
  k_patch<<<dim3(1024), dim3(384), 0, stream>>>(x, pe_w1, pe_w2, pe_b2, pos, h);
  k_lin_small<<<dim3(288), dim3(256), 0, stream>>>(sc, adaln_w, adaln_b, modAll, 18432);
  if (bigws)
    k_cvt_all<<<dim3(16800), dim3(256), 0, stream>>>(
        in_w, outp_w, mlp_w1, mlp_w2, xproj_w, wbfBase);

  for (int i = 0; i < 8; i++){
    const float* modL = modAll + (size_t)i*2304;
    bf16_t* wbf = bigws ? wbfBase + (size_t)i*2150400 : wbfBase;
    if (!bigws)
      k_cvt_layer<<<dim3(2100), dim3(256), 0, stream>>>(
          in_w + (size_t)i*147456, outp_w + (size_t)i*147456, mlp_w1 + (size_t)i*1179648,
          mlp_w2 + (size_t)i*589824, xproj_w + (size_t)i*86016, wbf);
    bf16_t* wbf_in  = wbf;
    bf16_t* wbf_out = wbf + 147456;
    bf16_t* wbf_w1  = wbf + 294912;
    bf16_t* wbf_w2  = wbf + 1474560;
    bf16_t* wbf_xp  = wbf + 2064384;

    // z = rms_mod(h, n1) @ in_w^T   [RMS fused into A-staging; only 6 col-blocks]
    k_gemm_bf<0,2><<<dim3(6,16), dim3(256), 0, stream>>>(
        h, wbf_in, nullptr, buf1, nullptr, n1_w + i*384, modL + 0, 384, 384, 384);
    k_conv<<<dim3(1024), dim3(384), 0, stream>>>(
        buf1, conv_w + (size_t)i*384*9, conv_b + i*384, convT, conv_bf);
    k_gemm_bf<0,0><<<dim3(4,16), dim3(256), 0, stream>>>(
        conv_bf, wbf_xp, nullptr, xdblS, nullptr, nullptr, nullptr, 224, 384, 224);
    k_scan<<<dim3(3072), dim3(256), 0, stream>>>(
        xdblS, convT, dt_w + (size_t)i*4*384*24, dt_b + (size_t)i*4*384,
        A_logs + (size_t)i*4*384*16, Ds + (size_t)i*4*384, ysT);
    k_merge_ln<<<dim3(1024), dim3(128), 0, stream>>>(
        ysT, onorm_w + i*384, onorm_b + i*384, ssin_bf);
    k_gemm_bf<2,0><<<dim3(6,16), dim3(256), 0, stream>>>(
        ssin_bf, wbf_out, nullptr, h, modL + 768, nullptr, nullptr, 384, 384, 384);
    k_rms_mod<<<dim3(1024), dim3(128), 0, stream>>>(h, n2_w + i*384, modL + 1152, xin_bf);
    // u12b = bf16(silu(u1)*u2), computed in the w1 GEMM epilogue (W rows interleaved)
    k_gemm_bf<4,0><<<dim3(48,16), dim3(256), 0, stream>>>(
        xin_bf, wbf_w1, mlp_b1 + (size_t)i*3072, (float*)u12b, nullptr, nullptr, nullptr,
        3072, 384, 3072);
    k_gemm_bf<5,0><<<dim3(6,16), dim3(256), 0, stream>>>(
        u12b, wbf_w2, mlp_b2 + (size_t)i*384, h, modL + 1920, nullptr, nullptr, 384, 1536, 384);
  }

  k_lin_small<<<dim3(12), dim3(256), 0, stream>>>(sc, f_adaln_w, f_adaln_b, modf, 768);
  k_final<<<dim3(1024), dim3(128), 0, stream>>>(h, modf, f_lin_w, f_lin_b, (float*)d_out);
}

// Round 11
// 1154.859 us; speedup vs baseline: 1.0350x; 1.0350x over previous
//
#include <hip/hip_runtime.h>
#include <hip/hip_bf16.h>
#include <math.h>

// dtype resolved empirically: all float inputs fp32, output fp32.
// GEMMs run as bf16 MFMA (threshold 2.5e-2 sized for bf16 compute; absmax 0.0078 @ R5/R6).
// R6 lesson: dt must be computed inside the scan (dtPre global round-trip = 3.4x FETCH).
// R7: B/C staged to LDS fp16 in phase 0 -> phases 1/3 pure LDS+math. 62->53us.
// R8 FAILED: 512-thread/2-d scan blocks (barrier radius doubled). 53->57us.
// R9 FAILED: RMS fused into wide-grid GEMM A-staging (48-colblock recompute).
// R10 WIN: SwiGLU row-interleave pack (MODE 4/5), u12 fp32->bf16. 1494->1307us.
// R11 WIN: all-layer cvt hoist + scan 2-d/block (shared B/C staging). 1307->1177us.
// R12: k_cond split WIN; scan 4-d/block FAILED (occupancy 52->19%). 2-d is the sweet spot.
// R13 WIN: scan reverted to R11 2-d verbatim. 1283->1159us. Best measured.
// R14 FAILED: ysT [b,k,l,d] scan stores = partial-line writes, WRITE_SIZE 4x. LESSON:
//     write-side coalescing first; scattered reads share L2 lines, scattered writes don't.
// R15 FAILED: rms1->gemm_in ASRC=2 fusion kept (+36us vs R13). LESSON: even narrow-grid
//     fusion-by-recompute loses when it puts a serial pre-pass at the block PROLOGUE;
//     only epilogue-side fusion (R10) or separate parallel dispatch wins.
// R16: exact R13 restore + k_final matvec parallelized (12 serial threads -> 48 threads,
//     4-way split-K + quad shfl reduce). [R16 bench was an infra failure; resubmitted as R17.]

#define DEV __device__ __forceinline__

typedef __bf16 bf16_t;
typedef __attribute__((ext_vector_type(8))) __bf16 bf16x8;
typedef __attribute__((ext_vector_type(4))) float f32x4;
typedef __attribute__((ext_vector_type(2))) _Float16 h2;

DEV float siluf(float x){ return x / (1.f + __expf(-x)); }
DEV float softplusf(float x){ return fmaxf(x, 0.f) + __logf(1.f + __expf(-fabsf(x))); }

// scan-order permutation: scan position l of direction k reads spatial row perm_idx(k,l)
DEV int perm_idx(int k, int l){
  switch(k & 3){
    case 0: return l;
    case 1: return 255 - l;
    case 2: return ((l & 15) << 4) | (l >> 4);
    default: { int r = 255 - l; return ((r & 15) << 4) | (r >> 4); }
  }
}

// ---------- weight fp32 -> bf16 cast ----------
// segments (elements): in_w 147456 | outp_w 147456 | mlp_w1 1179648 | mlp_w2 589824 | xproj 86016
// mlp_w1 rows interleaved for SwiGLU pack: dst row c: q=c>>5, t=c&31,
// src row = t<16 ? q*16+t : 1536 + q*16 + (t-16).
DEV void cvt_one(int idx, const float* inw, const float* outw, const float* w1,
                 const float* w2, const float* xp, bf16_t* dst){
  const float* src; int off;
  if (idx < 147456){ src = inw;  off = idx; }
  else if (idx < 294912){ src = outw; off = idx - 147456; }
  else if (idx < 1474560){
    int o = idx - 294912;
    int rowc = o / 384, col = o - rowc*384;
    int q = rowc >> 5, tt = rowc & 31;
    int srow = (tt < 16) ? (q*16 + tt) : (1536 + q*16 + (tt - 16));
    src = w1; off = srow*384 + col;
  }
  else if (idx < 2064384){ src = w2; off = idx - 1474560; }
  else { src = xp; off = idx - 2064384; }
  float4 v = *(const float4*)(src + off);
  union { bf16_t h[4]; uint2 u; } cv;
  cv.h[0] = (bf16_t)v.x; cv.h[1] = (bf16_t)v.y; cv.h[2] = (bf16_t)v.z; cv.h[3] = (bf16_t)v.w;
  *(uint2*)(dst + idx) = cv.u;
}

__global__ void k_cvt_layer(const float* __restrict__ inw, const float* __restrict__ outw,
                            const float* __restrict__ w1, const float* __restrict__ w2,
                            const float* __restrict__ xp, bf16_t* __restrict__ dst){
  int idx = (blockIdx.x*256 + threadIdx.x)*4;   // 2150400 per layer
  cvt_one(idx, inw, outw, w1, w2, xp, dst);
}

// all 8 layers in one dispatch: 2100 blocks per layer
__global__ void k_cvt_all(const float* __restrict__ inw, const float* __restrict__ outw,
                          const float* __restrict__ w1, const float* __restrict__ w2,
                          const float* __restrict__ xp, bf16_t* __restrict__ dst){
  int layer = blockIdx.x / 2100;
  int within = blockIdx.x % 2100;
  int idx = (within*256 + threadIdx.x)*4;
  cvt_one(idx, inw + (size_t)layer*147456, outw + (size_t)layer*147456,
          w1 + (size_t)layer*1179648, w2 + (size_t)layer*589824,
          xp + (size_t)layer*86016, dst + (size_t)layer*2150400);
}

// ---------- conditioning (R12: split + vectorized) ----------
__global__ void k_cond1(const float* __restrict__ t, const float* __restrict__ tw1,
                        const float* __restrict__ tb1, float* __restrict__ h1g){
  int b = blockIdx.x / 3, ch = blockIdx.x % 3;   // grid 12, block 128
  int tid = threadIdx.x;
  int o = ch*128 + tid;
  __shared__ float temb[256];
  float tv = t[b];
  {
    float f = __expf(-logf(10000.f) * (float)tid / 128.f);
    float a = tv * f;
    temb[tid] = cosf(a); temb[128 + tid] = sinf(a);
  }
  __syncthreads();
  const float4* te = (const float4*)temb;
  const float4* wp = (const float4*)(tw1 + (size_t)o*256);
  float acc = tb1[o];
  #pragma unroll 8
  for (int j = 0; j < 64; j++){
    float4 c4 = te[j], w4 = wp[j];
    acc += c4.x*w4.x + c4.y*w4.y + c4.z*w4.z + c4.w*w4.w;
  }
  h1g[b*384 + o] = siluf(acc);
}

__global__ void k_cond2(const int* __restrict__ y, const float* __restrict__ h1g,
                        const float* __restrict__ tw2, const float* __restrict__ tb2,
                        const float* __restrict__ ytab, float* __restrict__ sc){
  int b = blockIdx.x / 3, ch = blockIdx.x % 3;   // grid 12, block 128
  int tid = threadIdx.x;
  int o = ch*128 + tid;
  __shared__ float h1[384];
  h1[tid] = h1g[b*384 + tid];
  h1[tid + 128] = h1g[b*384 + tid + 128];
  h1[tid + 256] = h1g[b*384 + tid + 256];
  __syncthreads();
  const float4* hp = (const float4*)h1;
  const float4* wp = (const float4*)(tw2 + (size_t)o*384);
  float acc = tb2[o];
  #pragma unroll 8
  for (int j = 0; j < 96; j++){
    float4 c4 = hp[j], w4 = wp[j];
    acc += c4.x*w4.x + c4.y*w4.y + c4.z*w4.z + c4.w*w4.w;
  }
  float c = acc + ytab[(size_t)y[b]*384 + o];
  sc[b*384 + o] = siluf(c);
}

// ---------- patch embed + pos embed ----------
__global__ void k_patch(const float* __restrict__ x, const float* __restrict__ pw1,
                        const float* __restrict__ pw2, const float* __restrict__ pb2,
                        const float* __restrict__ pos, float* __restrict__ h){
  int bl = blockIdx.x; int b = bl >> 8; int l = bl & 255;
  int gh = l >> 4, gw = l & 15;
  __shared__ float xp[12]; __shared__ float tmp[128];
  int tid = threadIdx.x;  // block 384
  if (tid < 12){
    int ci = tid >> 2, ph = (tid >> 1) & 1, pw = tid & 1;
    xp[tid] = x[((size_t)(b*3 + ci)*32 + gh*2 + ph)*32 + gw*2 + pw];
  }
  __syncthreads();
  if (tid < 128){
    float a = 0.f;
    #pragma unroll
    for (int k = 0; k < 12; k++) a += xp[k] * pw1[tid*12 + k];
    tmp[tid] = a;
  }
  __syncthreads();
  float a = pb2[tid];
  for (int j = 0; j < 128; j++) a += tmp[j] * pw2[(size_t)tid*128 + j];
  h[(size_t)(b*256 + l)*384 + tid] = a + pos[(size_t)l*384 + tid];
}

// ---------- small linear ----------
__global__ void k_lin_small(const float* __restrict__ sc, const float* __restrict__ W,
                            const float* __restrict__ bias, float* __restrict__ out, int N){
  int idx = blockIdx.x * blockDim.x + threadIdx.x;
  if (idx >= 4*N) return;
  int b = idx / N, o = idx % N;
  const float4* cp = (const float4*)(sc + b*384);
  const float4* wp = (const float4*)(W + (size_t)o*384);
  float a = bias[o];
  #pragma unroll 4
  for (int k = 0; k < 96; k++){
    float4 c4 = cp[k], w4 = wp[k];
    a += c4.x*w4.x + c4.y*w4.y + c4.z*w4.z + c4.w*w4.w;
  }
  out[idx] = a;
}

// ---------- RMSNorm + adaLN modulate -> bf16 ----------
__global__ void k_rms_mod(const float* __restrict__ h, const float* __restrict__ nw,
                          const float* __restrict__ modBase, bf16_t* __restrict__ out){
  int bl = blockIdx.x; int b = bl >> 8;
  const float* hp = h + (size_t)bl*384;
  const float* mp = modBase + (size_t)b*18432;
  __shared__ float red[2];
  int tid = threadIdx.x;  // block 128
  float v[3]; float ss = 0.f;
  #pragma unroll
  for (int ii = 0; ii < 3; ii++){ v[ii] = hp[tid + ii*128]; ss += v[ii]*v[ii]; }
  #pragma unroll
  for (int off = 32; off; off >>= 1) ss += __shfl_down(ss, off);
  if ((tid & 63) == 0) red[tid >> 6] = ss;
  __syncthreads();
  ss = red[0] + red[1];
  float inv = rsqrtf(ss / 384.f + 1e-6f);
  #pragma unroll
  for (int ii = 0; ii < 3; ii++){
    int d = tid + ii*128;
    float xv = v[ii] * inv * nw[d];
    out[(size_t)bl*384 + d] = (bf16_t)(xv * (1.f + mp[384 + d]) + mp[d]);
  }
}

// ---------- bf16 MFMA GEMM: C[M,N] = A[M,K] @ W[N,K]^T ----------
// MODE 0: C = acc (fp32)
// MODE 2: C += gate*acc (gate = modBase[(row>>8)*18432 + col])
// MODE 4: SwiGLU pack (W rows pre-interleaved): Cb[row][p] = bf16(silu(u1+b[p])*(u2+b[N/2+p]))
// MODE 5: C += gate*(acc + bias)
template<int MODE>
__global__ __launch_bounds__(256) void k_gemm_bf(
    const bf16_t* __restrict__ A, const bf16_t* __restrict__ W,
    const float* __restrict__ bias, float* __restrict__ C,
    const float* __restrict__ modBase, int N, int K, int Nstore){
  __shared__ bf16_t As[2][64*40];
  __shared__ bf16_t Ws[2][64*40];
  const int tid = threadIdx.x;
  const int bm = blockIdx.y * 64, bn = blockIdx.x * 64;
  const int wave = tid >> 6, lane = tid & 63;
  const int m16 = lane & 15, kg = lane >> 4;
  const int r = tid >> 2, seg = tid & 3;
  const int nt = K / 32;

  uint4 aP, wP;
  auto loadT = [&](int kt){
    wP = *(const uint4*)(W + (size_t)(bn + r)*K + kt*32 + seg*8);
    aP = *(const uint4*)(A + (size_t)(bm + r)*K + kt*32 + seg*8);
  };
  auto stash = [&](int buf){
    *(uint4*)&As[buf][r*40 + seg*8] = aP;
    *(uint4*)&Ws[buf][r*40 + seg*8] = wP;
  };

  f32x4 acc[4] = {};
  loadT(0); stash(0); __syncthreads();
  for (int kt = 0; kt < nt; kt++){
    int buf = kt & 1;
    if (kt + 1 < nt) loadT(kt + 1);
    bf16x8 af = *(bf16x8*)&As[buf][(wave*16 + m16)*40 + kg*8];
    #pragma unroll
    for (int j = 0; j < 4; j++){
      bf16x8 bfr = *(bf16x8*)&Ws[buf][(j*16 + m16)*40 + kg*8];
      acc[j] = __builtin_amdgcn_mfma_f32_16x16x32_bf16(af, bfr, acc[j], 0, 0, 0);
    }
    if (kt + 1 < nt) stash(buf ^ 1);
    __syncthreads();
  }

  // C/D layout: col = lane&15, row = (lane>>4)*4 + reg
  if constexpr (MODE == 4){
    bf16_t* Cb = (bf16_t*)C;
    const int Np = N >> 1;    // 1536
    #pragma unroll
    for (int jp = 0; jp < 2; jp++){
      int pcol = (bn >> 1) + jp*16 + m16;
      float b1v = bias[pcol], b2v = bias[Np + pcol];
      #pragma unroll
      for (int rg = 0; rg < 4; rg++){
        int row = bm + wave*16 + kg*4 + rg;
        float u1v = acc[jp*2][rg] + b1v;
        float u2v = acc[jp*2 + 1][rg] + b2v;
        Cb[(size_t)row*Np + pcol] = (bf16_t)(siluf(u1v)*u2v);
      }
    }
  } else {
    #pragma unroll
    for (int j = 0; j < 4; j++){
      int col = bn + j*16 + m16;
      if (col < Nstore){
        #pragma unroll
        for (int rg = 0; rg < 4; rg++){
          int row = bm + wave*16 + kg*4 + rg;
          float v = acc[j][rg];
          if constexpr (MODE == 5) v += bias[col];
          if constexpr (MODE == 2 || MODE == 5)
            C[(size_t)row*N + col] += modBase[(size_t)(row >> 8)*18432 + col] * v;
          else
            C[(size_t)row*N + col] = v;
        }
      }
    }
  }
}

// ---------- depthwise 3x3 conv + bias + silu; writes fp32 + bf16 copies ----------
__global__ void k_conv(const float* __restrict__ z, const float* __restrict__ cw,
                       const float* __restrict__ cb, float* __restrict__ convT,
                       bf16_t* __restrict__ convB){
  int bl = blockIdx.x; int b = bl >> 8, l = bl & 255;
  int hh = l >> 4, ww = l & 15;
  int d = threadIdx.x;  // 384
  float acc = cb[d];
  #pragma unroll
  for (int kh = 0; kh < 3; kh++){
    int yy = hh + kh - 1; if ((unsigned)yy > 15u) continue;
    #pragma unroll
    for (int kw = 0; kw < 3; kw++){
      int xx = ww + kw - 1; if ((unsigned)xx > 15u) continue;
      acc += z[(size_t)(b*256 + yy*16 + xx)*384 + d] * cw[d*9 + kh*3 + kw];
    }
  }
  float s = siluf(acc);
  convT[(size_t)bl*384 + d] = s;
  convB[(size_t)bl*384 + d] = (bf16_t)s;
}

// ---------- fused dt + chunked selective scan -> ysT[b,k,d,l_scan] ----------
// xdblS layout: [b][lsp][224] cols k*56 + {dtr 0..23 | B 24..39 | C 40..55}
// R11 structure (measured best): 2 d-channels per 256-thread block (3072 blocks).
// B/C fp16 staging (18.4KB) shared by both d's; convT read as float2; phase 1/3 run
// two independent chains per thread; phase 2 uses 32 lanes. Barrier radius 256 (R8 lesson).
// Occupancy curve measured: 1-d/block 45% / 2-d 52% / 4-d 19%. 2-d wins.
// Output [b,k,d,l] COALESCED stores (R14 lesson: partial-line writes 4x WRITE_SIZE).
__global__ __launch_bounds__(256) void k_scan(
    const float* __restrict__ xdblS, const float* __restrict__ convT,
    const float* __restrict__ dtw, const float* __restrict__ dtb,
    const float* __restrict__ Alog, const float* __restrict__ Dsw,
    float* __restrict__ ysT){
  int blk = blockIdx.x;                 // b*768 + k*192 + dp
  int dp = blk % 192; int k = (blk / 192) & 3; int b = blk / 768;
  int d0 = dp*2;
  int tid = threadIdx.x;
  int n = tid & 15, chunk = tid >> 4;
  __shared__ float sdt[2][256], sxv[2][256], sy[2][256];
  __shared__ float sA[2][16][17], sBc[2][16][17], sPre[2][16][17];
  __shared__ _Float16 sB16[256*18];
  __shared__ _Float16 sC16[256*18];

  // phase 0: dt = softplus(dtr . dtw_row + dtb) for both d's; stage x2, B, C
  {
    int l = tid;
    int lp = perm_idx(k, l);
    const float* row = xdblS + (size_t)(b*256 + lp)*224 + k*56;
    const float4* xr = (const float4*)(row);
    float4 x0 = xr[0], x1 = xr[1], x2 = xr[2], x3 = xr[3], x4 = xr[4], x5 = xr[5];
    #pragma unroll
    for (int j = 0; j < 2; j++){
      const float4* w = (const float4*)(dtw + ((size_t)k*384 + d0 + j)*24);
      float4 w0 = w[0], w1 = w[1], w2 = w[2], w3 = w[3], w4 = w[4], w5 = w[5];
      float a0 = dtb[k*384 + d0 + j];
      a0 += x0.x*w0.x + x0.y*w0.y + x0.z*w0.z + x0.w*w0.w;
      a0 += x1.x*w1.x + x1.y*w1.y + x1.z*w1.z + x1.w*w1.w;
      a0 += x2.x*w2.x + x2.y*w2.y + x2.z*w2.z + x2.w*w2.w;
      a0 += x3.x*w3.x + x3.y*w3.y + x3.z*w3.z + x3.w*w3.w;
      a0 += x4.x*w4.x + x4.y*w4.y + x4.z*w4.z + x4.w*w4.w;
      a0 += x5.x*w5.x + x5.y*w5.y + x5.z*w5.z + x5.w*w5.w;
      sdt[j][l] = softplusf(a0);
    }
    float2 xv2 = *(const float2*)(convT + (size_t)(b*256 + lp)*384 + d0);
    sxv[0][l] = xv2.x; sxv[1][l] = xv2.y;
    const float4* bp = (const float4*)(row + 24);   // bp[0..3]=B, bp[4..7]=C
    h2* bl = (h2*)(sB16 + l*18);
    h2* cl = (h2*)(sC16 + l*18);
    #pragma unroll
    for (int q = 0; q < 4; q++){
      float4 bv = bp[q];
      h2 p0; p0[0] = (_Float16)bv.x; p0[1] = (_Float16)bv.y;
      h2 p1; p1[0] = (_Float16)bv.z; p1[1] = (_Float16)bv.w;
      bl[q*2] = p0; bl[q*2+1] = p1;
      float4 cv = bp[q+4];
      h2 q0; q0[0] = (_Float16)cv.x; q0[1] = (_Float16)cv.y;
      h2 q1; q1[0] = (_Float16)cv.z; q1[1] = (_Float16)cv.w;
      cl[q*2] = q0; cl[q*2+1] = q1;
    }
  }
  __syncthreads();

  float av[2], Dv[2];
  #pragma unroll
  for (int j = 0; j < 2; j++){
    av[j] = -__expf(Alog[((size_t)(k*384) + d0 + j)*16 + n]);
    Dv[j] = Dsw[k*384 + d0 + j];
  }

  // phase 1: local chunk scan from zero state, two chains
  float dA[2][16], dBu[2][16];
  float Ap[2] = {1.f, 1.f}, hl[2] = {0.f, 0.f};
  #pragma unroll
  for (int i = 0; i < 16; i++){
    int l = chunk*16 + i;
    float bn16 = (float)sB16[l*18 + n];
    #pragma unroll
    for (int j = 0; j < 2; j++){
      float dtv = sdt[j][l];
      float e = __expf(dtv * av[j]);
      float u = dtv * sxv[j][l] * bn16;
      dA[j][i] = e; dBu[j][i] = u;
      Ap[j] *= e; hl[j] = e*hl[j] + u;
    }
  }
  #pragma unroll
  for (int j = 0; j < 2; j++){ sA[j][chunk][n] = Ap[j]; sBc[j][chunk][n] = hl[j]; }
  __syncthreads();

  // phase 2: carry scan across 16 chunks (32 lanes: 16 per d)
  if (tid < 32){
    int j = tid >> 4, nn = tid & 15;
    float carry = 0.f;
    #pragma unroll
    for (int c = 0; c < 16; c++){
      sPre[j][c][nn] = carry;
      carry = sA[j][c][nn]*carry + sBc[j][c][nn];
    }
  }
  __syncthreads();

  // phase 3: replay; reduce over n; stage into sy
  float hh[2] = {sPre[0][chunk][n], sPre[1][chunk][n]};
  #pragma unroll
  for (int i = 0; i < 16; i++){
    int l = chunk*16 + i;
    float cn = (float)sC16[l*18 + n];
    hh[0] = dA[0][i]*hh[0] + dBu[0][i];
    hh[1] = dA[1][i]*hh[1] + dBu[1][i];
    float p0 = hh[0]*cn, p1 = hh[1]*cn;
    p0 += __shfl_xor(p0, 1); p1 += __shfl_xor(p1, 1);
    p0 += __shfl_xor(p0, 2); p1 += __shfl_xor(p1, 2);
    p0 += __shfl_xor(p0, 4); p1 += __shfl_xor(p1, 4);
    p0 += __shfl_xor(p0, 8); p1 += __shfl_xor(p1, 8);
    if (n == 0){
      sy[0][l] = p0 + Dv[0]*sxv[0][l];
      sy[1][l] = p1 + Dv[1]*sxv[1][l];
    }
  }
  __syncthreads();
  // coalesced writes: ysT[b,k,d,l]
  ysT[((size_t)(b*4 + k)*384 + d0)*256 + tid] = sy[0][tid];
  ysT[((size_t)(b*4 + k)*384 + d0 + 1)*256 + tid] = sy[1][tid];
}

// ---------- merge 4 directions + LayerNorm(onorm) -> bf16 (ysT[b,k,d,l_scan]) ----------
__global__ void k_merge_ln(const float* __restrict__ ysT, const float* __restrict__ ow,
                           const float* __restrict__ ob, bf16_t* __restrict__ out){
  int bl = blockIdx.x; int b = bl >> 8; int l = bl & 255;
  int tl = ((l & 15) << 4) | (l >> 4);
  int i2 = 255 - l, i4 = 255 - tl;
  __shared__ float red[4];
  int tid = threadIdx.x;  // block 128
  const float* base = ysT + (size_t)b*4*384*256;
  float v[3]; float s = 0.f, s2 = 0.f;
  #pragma unroll
  for (int ii = 0; ii < 3; ii++){
    int d = tid + ii*128;
    float vv = base[(size_t)d*256 + l]
             + base[(size_t)(384 + d)*256 + i2]
             + base[(size_t)(768 + d)*256 + tl]
             + base[(size_t)(1152 + d)*256 + i4];
    v[ii] = vv; s += vv; s2 += vv*vv;
  }
  #pragma unroll
  for (int off = 32; off; off >>= 1){ s += __shfl_down(s, off); s2 += __shfl_down(s2, off); }
  if ((tid & 63) == 0){ red[tid >> 6] = s; red[2 + (tid >> 6)] = s2; }
  __syncthreads();
  s = red[0] + red[1]; s2 = red[2] + red[3];
  float mu = s / 384.f;
  float var = s2 / 384.f - mu*mu;
  float inv = rsqrtf(var + 1e-5f);
  #pragma unroll
  for (int ii = 0; ii < 3; ii++){
    int d = tid + ii*128;
    out[(size_t)bl*384 + d] = (bf16_t)((v[ii] - mu) * inv * ow[d] + ob[d]);
  }
}

// ---------- final: ln_na + modulate + f_lin + unpatchify ----------
// R16: output matvec parallelized: 48 threads (12 outputs x 4-way split-K),
// quad shfl_xor reduce; was 12 threads x serial 384-MAC.
__global__ void k_final(const float* __restrict__ h, const float* __restrict__ modf,
                        const float* __restrict__ flw, const float* __restrict__ flb,
                        float* __restrict__ out){
  int bl = blockIdx.x; int b = bl >> 8; int l = bl & 255;
  int tid = threadIdx.x;  // block 128
  __shared__ float buf[384]; __shared__ float red[4];
  const float* hp = h + (size_t)bl*384;
  float v[3]; float s = 0.f, s2 = 0.f;
  #pragma unroll
  for (int ii = 0; ii < 3; ii++){ float xv = hp[tid + ii*128]; v[ii] = xv; s += xv; s2 += xv*xv; }
  #pragma unroll
  for (int off = 32; off; off >>= 1){ s += __shfl_down(s, off); s2 += __shfl_down(s2, off); }
  if ((tid & 63) == 0){ red[tid >> 6] = s; red[2 + (tid >> 6)] = s2; }
  __syncthreads();
  s = red[0] + red[1]; s2 = red[2] + red[3];
  float mu = s / 384.f;
  float var = s2 / 384.f - mu*mu;
  float inv = rsqrtf(var + 1e-6f);
  #pragma unroll
  for (int ii = 0; ii < 3; ii++){
    int d = tid + ii*128;
    buf[d] = (v[ii] - mu) * inv * (1.f + modf[b*768 + 384 + d]) + modf[b*768 + d];
  }
  __syncthreads();
  if (tid < 48){
    int o = tid >> 2, part = tid & 3;
    const float4* bp = (const float4*)(buf + part*96);
    const float4* wp = (const float4*)(flw + (size_t)o*384 + part*96);
    float a = 0.f;
    #pragma unroll
    for (int kk = 0; kk < 24; kk++){
      float4 c4 = bp[kk], w4 = wp[kk];
      a += c4.x*w4.x + c4.y*w4.y + c4.z*w4.z + c4.w*w4.w;
    }
    a += __shfl_xor(a, 1);
    a += __shfl_xor(a, 2);
    if (part == 0){
      a += flb[o];
      int p = o / 6, q = (o / 3) & 1, cc = o % 3;
      int gh = l >> 4, gw = l & 15;
      out[((size_t)(b*3 + cc)*32 + gh*2 + p)*32 + gw*2 + q] = a;
    }
  }
}

extern "C" void kernel_launch(void* const* d_in, const int* in_sizes, int n_in,
                              void* d_out, int out_size, void* d_ws, size_t ws_size,
                              hipStream_t stream){
  const float* x       = (const float*)d_in[0];
  const float* t       = (const float*)d_in[1];
  const int*   y       = (const int*)  d_in[2];
  const float* t_w1    = (const float*)d_in[3];
  const float* t_b1    = (const float*)d_in[4];
  const float* t_w2    = (const float*)d_in[5];
  const float* t_b2    = (const float*)d_in[6];
  const float* y_table = (const float*)d_in[7];
  const float* pe_w1   = (const float*)d_in[8];
  const float* pe_w2   = (const float*)d_in[9];
  const float* pe_b2   = (const float*)d_in[10];
  const float* pos     = (const float*)d_in[11];
  const float* adaln_w = (const float*)d_in[12];
  const float* adaln_b = (const float*)d_in[13];
  const float* n1_w    = (const float*)d_in[14];
  const float* n2_w    = (const float*)d_in[15];
  const float* in_w    = (const float*)d_in[16];
  const float* conv_w  = (const float*)d_in[17];
  const float* conv_b  = (const float*)d_in[18];
  const float* xproj_w = (const float*)d_in[19];
  const float* dt_w    = (const float*)d_in[20];
  const float* dt_b    = (const float*)d_in[21];
  const float* A_logs  = (const float*)d_in[22];
  const float* Ds      = (const float*)d_in[23];
  const float* onorm_w = (const float*)d_in[24];
  const float* onorm_b = (const float*)d_in[25];
  const float* outp_w  = (const float*)d_in[26];
  const float* mlp_w1  = (const float*)d_in[27];
  const float* mlp_b1  = (const float*)d_in[28];
  const float* mlp_w2  = (const float*)d_in[29];
  const float* mlp_b2  = (const float*)d_in[30];
  const float* f_adaln_w = (const float*)d_in[31];
  const float* f_adaln_b = (const float*)d_in[32];
  const float* f_lin_w = (const float*)d_in[33];
  const float* f_lin_b = (const float*)d_in[34];

  float* ws = (float*)d_ws;
  float*  sc      = ws + 0;         // 1536
  float*  h       = ws + 1536;      // 393216
  float*  modAll  = ws + 394752;    // 73728 (4 x 18432)
  float*  modf    = ws + 468480;    // 3072
  float*  buf1    = ws + 471552;    // 393216 (z)
  float*  convT   = ws + 864768;    // 393216
  float*  xdblS   = ws + 1257984;   // 229376 (4 x 256 x 224)
  bf16_t* u12b    = (bf16_t*)(ws + 1487360);   // 1572864 bf16 (786432 fl)
  float*  ysT     = ws + 2273792;   // 1572864 (layout [b][k][d][l])
  bf16_t* xin_bf  = (bf16_t*)(ws + 3846656);   // 393216 bf16
  bf16_t* ssin_bf = (bf16_t*)(ws + 4043264);   // 393216 bf16
  bf16_t* conv_bf = (bf16_t*)(ws + 4239872);   // 393216 bf16
  bf16_t* wbfBase = (bf16_t*)(ws + 4436480);   // big: 8x2150400 bf16; small: 1x
  float*  h1g     = ysT;            // 1536 fl scratch (ysT unused until first scan)

  const bool bigws = ws_size >= (size_t)13038080 * 4;

  k_cond1<<<dim3(12), dim3(128), 0, stream>>>(t, t_w1, t_b1, h1g);
  k_cond2<<<dim3(12), dim3(128), 0, stream>>>(y, h1g, t_w2, t_b2, y_table, sc);
  k_patch<<<dim3(1024), dim3(384), 0, stream>>>(x, pe_w1, pe_w2, pe_b2, pos, h);
  k_lin_small<<<dim3(288), dim3(256), 0, stream>>>(sc, adaln_w, adaln_b, modAll, 18432);
  if (bigws)
    k_cvt_all<<<dim3(16800), dim3(256), 0, stream>>>(
        in_w, outp_w, mlp_w1, mlp_w2, xproj_w, wbfBase);

  for (int i = 0; i < 8; i++){
    const float* modL = modAll + (size_t)i*2304;
    bf16_t* wbf = bigws ? wbfBase + (size_t)i*2150400 : wbfBase;
    if (!bigws)
      k_cvt_layer<<<dim3(2100), dim3(256), 0, stream>>>(
          in_w + (size_t)i*147456, outp_w + (size_t)i*147456, mlp_w1 + (size_t)i*1179648,
          mlp_w2 + (size_t)i*589824, xproj_w + (size_t)i*86016, wbf);
    bf16_t* wbf_in  = wbf;
    bf16_t* wbf_out = wbf + 147456;
    bf16_t* wbf_w1  = wbf + 294912;
    bf16_t* wbf_w2  = wbf + 1474560;
    bf16_t* wbf_xp  = wbf + 2064384;

    k_rms_mod<<<dim3(1024), dim3(128), 0, stream>>>(h, n1_w + i*384, modL + 0, xin_bf);
    k_gemm_bf<0><<<dim3(6,16), dim3(256), 0, stream>>>(
        xin_bf, wbf_in, nullptr, buf1, nullptr, 384, 384, 384);
    k_conv<<<dim3(1024), dim3(384), 0, stream>>>(
        buf1, conv_w + (size_t)i*384*9, conv_b + i*384, convT, conv_bf);
    k_gemm_bf<0><<<dim3(4,16), dim3(256), 0, stream>>>(
        conv_bf, wbf_xp, nullptr, xdblS, nullptr, 224, 384, 224);
    k_scan<<<dim3(3072), dim3(256), 0, stream>>>(
        xdblS, convT, dt_w + (size_t)i*4*384*24, dt_b + (size_t)i*4*384,
        A_logs + (size_t)i*4*384*16, Ds + (size_t)i*4*384, ysT);
    k_merge_ln<<<dim3(1024), dim3(128), 0, stream>>>(
        ysT, onorm_w + i*384, onorm_b + i*384, ssin_bf);
    k_gemm_bf<2><<<dim3(6,16), dim3(256), 0, stream>>>(
        ssin_bf, wbf_out, nullptr, h, modL + 768, 384, 384, 384);
    k_rms_mod<<<dim3(1024), dim3(128), 0, stream>>>(h, n2_w + i*384, modL + 1152, xin_bf);
    // u12b = bf16(silu(u1)*u2), computed in the w1 GEMM epilogue (W rows interleaved)
    k_gemm_bf<4><<<dim3(48,16), dim3(256), 0, stream>>>(
        xin_bf, wbf_w1, mlp_b1 + (size_t)i*3072, (float*)u12b, nullptr, 3072, 384, 3072);
    k_gemm_bf<5><<<dim3(6,16), dim3(256), 0, stream>>>(
        u12b, wbf_w2, mlp_b2 + (size_t)i*384, h, modL + 1920, 384, 1536, 384);
  }

  k_lin_small<<<dim3(12), dim3(256), 0, stream>>>(sc, f_adaln_w, f_adaln_b, modf, 768);
  k_final<<<dim3(1024), dim3(128), 0, stream>>>(h, modf, f_lin_w, f_lin_b, (float*)d_out);
}